// Round 10
// baseline (10049.795 us; speedup 1.0000x reference)
//
#include <hip/hip_runtime.h>
#include <cstdint>
#include <cstddef>

typedef _Float16 f16;
typedef _Float16 f16x8 __attribute__((ext_vector_type(8)));
typedef float f32x4 __attribute__((ext_vector_type(4)));
typedef unsigned int u32;
typedef unsigned short u16;
typedef u32 u32x4 __attribute__((ext_vector_type(4)));

#define NB 256
#define NT 256
#define ND 128
#define NH 512
#define NG 1536
#define NOUT 24
#define PL (NB * NH)  // one exchange plane (u32 elements)

__device__ __forceinline__ float fsig(float x) {
  float e = __expf(-x);
  return __fdividef(1.0f, 1.0f + e);
}
__device__ __forceinline__ float ftanh(float x) {
  float ax = __builtin_fabsf(x);
  float e = __expf(-2.0f * ax);
  float t = __fdividef(1.0f - e, 1.0f + e);
  return __builtin_copysignf(t, x);
}
__device__ __forceinline__ float f16lo(u32 v) {
  union { u16 s; f16 f; } u; u.s = (u16)(v & 0xffffu); return (float)u.f;
}
__device__ __forceinline__ u16 f16bits(f16 v) {
  union { f16 f; u16 s; } u; u.f = v; return u.s;
}

__global__ void k_f32_to_f16(const float* __restrict__ in, f16* __restrict__ out, int n) {
  int stride = gridDim.x * blockDim.x;
  for (int i = blockIdx.x * blockDim.x + threadIdx.x; i < n; i += stride)
    out[i] = (f16)in[i];
}

__device__ __forceinline__ f16x8 ld8(const f16* p) { return *(const f16x8*)p; }
__device__ __forceinline__ f16x8 ld8(const float* p) {
  float4 a = *(const float4*)p;
  float4 b = *(const float4*)(p + 4);
  f16x8 o;
  o[0] = (f16)a.x; o[1] = (f16)a.y; o[2] = (f16)a.z; o[3] = (f16)a.w;
  o[4] = (f16)b.x; o[5] = (f16)b.y; o[6] = (f16)b.z; o[7] = (f16)b.w;
  return o;
}

// ---- gx = A @ W^T + b. M-index r -> batch b=r>>tsh, local t = r&mask. (proven r7-r9)
template <int K, typename TA>
__global__ __launch_bounds__(256) void k_gemm(
    const TA* __restrict__ A, const f16* __restrict__ W,
    const float* __restrict__ bias, f16* __restrict__ gx, int t0, int tsh) {
  const int tid = threadIdx.x;
  const int wave = tid >> 6, lane = tid & 63;
  const int wm = wave >> 1, wn = wave & 1;
  const int m0 = blockIdx.x * 128 + wm * 64;
  const int n0 = blockIdx.y * 64 + wn * 32;
  const int lr = lane & 15;
  const int lk = (lane >> 4) * 8;
  const int tmask = (1 << tsh) - 1;

  f32x4 acc[4][2];
#pragma unroll
  for (int i = 0; i < 4; i++)
#pragma unroll
    for (int jj = 0; jj < 2; jj++) acc[i][jj] = (f32x4){0.f, 0.f, 0.f, 0.f};

  const TA* Ap[4];
#pragma unroll
  for (int i = 0; i < 4; i++) {
    int r = m0 + i * 16 + lr;
    int arow = ((r >> tsh) << 8) + t0 + (r & tmask);
    Ap[i] = A + (size_t)arow * K + lk;
  }
  const f16* Wp = W + (size_t)(n0 + lr) * K + lk;
  for (int k0 = 0; k0 < K; k0 += 32) {
    f16x8 a[4], b[2];
#pragma unroll
    for (int i = 0; i < 4; i++) a[i] = ld8(Ap[i] + k0);
#pragma unroll
    for (int jj = 0; jj < 2; jj++) b[jj] = *(const f16x8*)(Wp + (size_t)(jj * 16) * K + k0);
#pragma unroll
    for (int i = 0; i < 4; i++)
#pragma unroll
      for (int jj = 0; jj < 2; jj++)
        acc[i][jj] = __builtin_amdgcn_mfma_f32_16x16x32_f16(a[i], b[jj], acc[i][jj], 0, 0, 0);
  }
  const int rowb = (lane >> 4) * 4;
#pragma unroll
  for (int jj = 0; jj < 2; jj++) {
    int col = n0 + jj * 16 + lr;
    float bv = bias[col];
#pragma unroll
    for (int i = 0; i < 4; i++)
#pragma unroll
      for (int r = 0; r < 4; r++) {
        int row = m0 + i * 16 + rowb + r;
        gx[(size_t)row * NG + col] = (f16)(acc[i][jj][r] + bv);
      }
  }
}

// issue one 4-kk batch from plane base_ (8 dwordx4, system-coherent)
#define ISSUEP(qarr, base_, kkb)                                          \
  _Pragma("unroll") for (int u_ = 0; u_ < 4; u_++) {                      \
    const u32* pp_ = base_ + (kkb + u_) * 32 + lkh * 8;                   \
    asm volatile("global_load_dwordx4 %0, %1, off sc0 sc1"                \
                 : "=v"(qarr[2 * u_]) : "v"(pp_));                        \
    asm volatile("global_load_dwordx4 %0, %1, off sc0 sc1"                \
                 : "=v"(qarr[2 * u_ + 1]) : "v"(pp_ + 4));                \
  }

// tag-verify both planes of a batch; stale -> reissue + drain + recheck
#define VERIFY(qh, ql, kkb)                                                \
  for (;;) {                                                               \
    u32 d_ = 0;                                                            \
    _Pragma("unroll") for (int u_ = 0; u_ < 8; u_++) {                     \
      d_ |= __builtin_amdgcn_perm(qh[u_][1], qh[u_][0], 0x07060302u) ^ expectp; \
      d_ |= __builtin_amdgcn_perm(qh[u_][3], qh[u_][2], 0x07060302u) ^ expectp; \
      d_ |= __builtin_amdgcn_perm(ql[u_][1], ql[u_][0], 0x07060302u) ^ expectp; \
      d_ |= __builtin_amdgcn_perm(ql[u_][3], ql[u_][2], 0x07060302u) ^ expectp; \
    }                                                                      \
    if (__all(d_ == 0)) break;                                             \
    __builtin_amdgcn_s_sleep(1);                                           \
    ISSUEP(qh, hq, kkb);                                                   \
    ISSUEP(ql, lq, kkb);                                                   \
    asm volatile("s_waitcnt vmcnt(0)" ::: "memory");                       \
    __builtin_amdgcn_sched_barrier(0);                                     \
  }

// consume one 4-kk batch: low-half f16s -> hi/lo A-fragments, 6 MFMA per kk
#define CONSUMEB(qh, ql, kkb)                                              \
  _Pragma("unroll") for (int u_ = 0; u_ < 4; u_++) {                       \
    const int kk_ = kkb + u_;                                              \
    union { u32 w[4]; f16x8 v; } AH_, AL_;                                 \
    AH_.w[0] = __builtin_amdgcn_perm(qh[2*u_][1],   qh[2*u_][0],   0x05040100u); \
    AH_.w[1] = __builtin_amdgcn_perm(qh[2*u_][3],   qh[2*u_][2],   0x05040100u); \
    AH_.w[2] = __builtin_amdgcn_perm(qh[2*u_+1][1], qh[2*u_+1][0], 0x05040100u); \
    AH_.w[3] = __builtin_amdgcn_perm(qh[2*u_+1][3], qh[2*u_+1][2], 0x05040100u); \
    AL_.w[0] = __builtin_amdgcn_perm(ql[2*u_][1],   ql[2*u_][0],   0x05040100u); \
    AL_.w[1] = __builtin_amdgcn_perm(ql[2*u_][3],   ql[2*u_][2],   0x05040100u); \
    AL_.w[2] = __builtin_amdgcn_perm(ql[2*u_+1][1], ql[2*u_+1][0], 0x05040100u); \
    AL_.w[3] = __builtin_amdgcn_perm(ql[2*u_+1][3], ql[2*u_+1][2], 0x05040100u); \
    const int co_ = (((kk_ * 4 + lkh) ^ swz) << 3);                        \
    f16x8 br_ = *(const f16x8*)(wr_ + co_);                                \
    f16x8 bz_ = *(const f16x8*)(wz_ + co_);                                \
    f16x8 bn_ = *(const f16x8*)(wn_ + co_);                                \
    ar = __builtin_amdgcn_mfma_f32_16x16x32_f16(AH_.v, br_, ar, 0, 0, 0);  \
    az = __builtin_amdgcn_mfma_f32_16x16x32_f16(AH_.v, bz_, az, 0, 0, 0);  \
    an = __builtin_amdgcn_mfma_f32_16x16x32_f16(AH_.v, bn_, an, 0, 0, 0);  \
    ar = __builtin_amdgcn_mfma_f32_16x16x32_f16(AL_.v, br_, ar, 0, 0, 0);  \
    az = __builtin_amdgcn_mfma_f32_16x16x32_f16(AL_.v, bz_, az, 0, 0, 0);  \
    an = __builtin_amdgcn_mfma_f32_16x16x32_f16(AL_.v, bn_, an, 0, 0, 0);  \
  }

// ---- GRU recurrence, self-tagged dataflow. 128 blocks = 8 groups x 16 slices.
// No barriers, no flags: each exchange u32 = (tag16<<16)|f16bits, tag = step+1.
// Consumers verify tags on the loads themselves; producers just store.
__global__ __launch_bounds__(256, 1) void k_rec(
    const f16* __restrict__ gx, const f16* __restrict__ whh, const float* __restrict__ bhh,
    f16* __restrict__ h, u32* __restrict__ exqH, u32* __restrict__ exqL,
    int t0, int Tc) {
  __shared__ f16 wlds[96 * 512];
  const int tid = threadIdx.x;
  const int g = blockIdx.x >> 4;
  const int cs = blockIdx.x & 15;
  const int b0 = g * 32, c0 = cs * 32;
  const int lane = tid & 63, wave = tid >> 6;
  const int wm = wave >> 1, wn = wave & 1;
  const int lr = lane & 15, lkh = lane >> 4;

  for (int idx = tid; idx < 96 * 64; idx += 256) {
    int lrw = idx >> 6, c = idx & 63;
    int grow = (lrw >> 5) * NH + c0 + (lrw & 31);
    f16x8 v = *(const f16x8*)(whh + (size_t)grow * NH + c * 8);
    *(f16x8*)(wlds + lrw * 512 + ((c ^ (lrw & 7)) << 3)) = v;
  }
  __syncthreads();

  const int jloc = wn * 16 + lr;
  const int j = c0 + jloc;
  const float bh_r = bhh[j], bh_z = bhh[NH + j], bh_n = bhh[2 * NH + j];
  const int arow = b0 + wm * 16 + lr;
  const int rowbase = b0 + wm * 16 + lkh * 4;
  const int swz = jloc & 7;
  const f16* wr_ = wlds + jloc * 512;
  const f16* wz_ = wlds + (32 + jloc) * 512;
  const f16* wn_ = wlds + (64 + jloc) * 512;

  const int tend = t0 + Tc;
  float hold[4];
  if (t0 == 0) {
#pragma unroll
    for (int r = 0; r < 4; r++) hold[r] = 0.f;
  } else {
    const u32* ph = exqH + (size_t)((t0 - 1) & 1) * PL;
    const u32* pl_ = exqL + (size_t)((t0 - 1) & 1) * PL;
#pragma unroll
    for (int r = 0; r < 4; r++) {
      u32 vh = __hip_atomic_load(ph + (size_t)(rowbase + r) * NH + j,
                                 __ATOMIC_RELAXED, __HIP_MEMORY_SCOPE_AGENT);
      u32 vl = __hip_atomic_load(pl_ + (size_t)(rowbase + r) * NH + j,
                                 __ATOMIC_RELAXED, __HIP_MEMORY_SCOPE_AGENT);
      hold[r] = f16lo(vh) + f16lo(vl);
    }
  }

  // gx prefetch for first step
  float xr[4], xz[4], xn[4];
#pragma unroll
  for (int r = 0; r < 4; r++) {
    const f16* gp = gx + ((size_t)(rowbase + r) * Tc) * NG + j;
    xr[r] = (float)gp[0]; xz[r] = (float)gp[NH]; xn[r] = (float)gp[2 * NH];
  }

  for (int t = t0; t < tend; t++) {
    f32x4 ar = {0.f, 0.f, 0.f, 0.f}, az = {0.f, 0.f, 0.f, 0.f}, an = {0.f, 0.f, 0.f, 0.f};
    if (t > 0) {
      const u32* hq = exqH + (size_t)((t ^ 1) & 1) * PL + (size_t)arow * NH;
      const u32* lq = exqL + (size_t)((t ^ 1) & 1) * PL + (size_t)arow * NH;
      const u32 expectp = (u32)t * 0x10001u;
      u32x4 qAh[8], qAl[8], qBh[8], qBl[8];
      ISSUEP(qAh, hq, 0); ISSUEP(qAl, lq, 0);
      ISSUEP(qBh, hq, 4); ISSUEP(qBl, lq, 4);
      asm volatile("s_waitcnt vmcnt(16)" ::: "memory");
      __builtin_amdgcn_sched_barrier(0);
      VERIFY(qAh, qAl, 0);
      CONSUMEB(qAh, qAl, 0);
      ISSUEP(qAh, hq, 8); ISSUEP(qAl, lq, 8);
      asm volatile("s_waitcnt vmcnt(16)" ::: "memory");
      __builtin_amdgcn_sched_barrier(0);
      VERIFY(qBh, qBl, 4);
      CONSUMEB(qBh, qBl, 4);
      ISSUEP(qBh, hq, 12); ISSUEP(qBl, lq, 12);
      asm volatile("s_waitcnt vmcnt(16)" ::: "memory");
      __builtin_amdgcn_sched_barrier(0);
      VERIFY(qAh, qAl, 8);
      CONSUMEB(qAh, qAl, 8);
      asm volatile("s_waitcnt vmcnt(0)" ::: "memory");
      __builtin_amdgcn_sched_barrier(0);
      VERIFY(qBh, qBl, 12);
      CONSUMEB(qBh, qBl, 12);
    }
    // gates + tagged publish (no drain, no barrier, no flag)
    u32* oH = exqH + (size_t)(t & 1) * PL;
    u32* oL = exqL + (size_t)(t & 1) * PL;
    const u32 tagw = (u32)(t + 1) << 16;
#pragma unroll
    for (int r = 0; r < 4; r++) {
      float rg = fsig(xr[r] + ar[r] + bh_r);
      float zg = fsig(xz[r] + az[r] + bh_z);
      float ng = ftanh(xn[r] + rg * (an[r] + bh_n));
      float hnew = ng + zg * (hold[r] - ng);
      hold[r] = hnew;
      f16 hi = (f16)hnew;
      f16 lo = (f16)(hnew - (float)hi);
      const size_t oidx = (size_t)(rowbase + r) * NH + j;
      __hip_atomic_store(oH + oidx, tagw | (u32)f16bits(hi),
                         __ATOMIC_RELAXED, __HIP_MEMORY_SCOPE_AGENT);
      __hip_atomic_store(oL + oidx, tagw | (u32)f16bits(lo),
                         __ATOMIC_RELAXED, __HIP_MEMORY_SCOPE_AGENT);
      h[((size_t)(rowbase + r) * NT + t) * NH + j] = hi;
    }
    if (t + 1 < tend) {  // gx prefetch for next step (overlaps next spin)
#pragma unroll
      for (int r = 0; r < 4; r++) {
        const f16* gp = gx + ((size_t)(rowbase + r) * Tc + (t + 1 - t0)) * NG + j;
        xr[r] = (float)gp[0]; xz[r] = (float)gp[NH]; xn[r] = (float)gp[2 * NH];
      }
    }
  }
}

// ---- final FC
__global__ void k_fc(const f16* __restrict__ h, const float* __restrict__ fcw,
                     const float* __restrict__ fcb, float* __restrict__ out) {
  int b = blockIdx.x;
  int lane = threadIdx.x;  // 64
  __shared__ float hrow[NH];
  for (int k = lane; k < NH; k += 64)
    hrow[k] = (float)h[((size_t)b * NT + (NT - 1)) * NH + k];
  __syncthreads();
  for (int o = 0; o < NOUT; o++) {
    float sm = 0.f;
    for (int k = lane; k < NH; k += 64) sm += hrow[k] * fcw[o * NH + k];
#pragma unroll
    for (int off = 32; off; off >>= 1) sm += __shfl_down(sm, off);
    if (lane == 0) out[b * NOUT + o] = sm + fcb[o];
  }
}

extern "C" void kernel_launch(void* const* d_in, const int* in_sizes, int n_in,
                              void* d_out, int out_size, void* d_ws, size_t ws_size,
                              hipStream_t stream) {
  (void)in_sizes; (void)n_in; (void)out_size;
  const float* x = (const float*)d_in[0];
  const float* w_ih[3] = {(const float*)d_in[1], (const float*)d_in[5], (const float*)d_in[9]};
  const float* w_hh[3] = {(const float*)d_in[2], (const float*)d_in[6], (const float*)d_in[10]};
  const float* b_ih[3] = {(const float*)d_in[3], (const float*)d_in[7], (const float*)d_in[11]};
  const float* b_hh[3] = {(const float*)d_in[4], (const float*)d_in[8], (const float*)d_in[12]};
  const float* fcw = (const float*)d_in[13];
  const float* fcb = (const float*)d_in[14];

  const size_t exq_layer = (size_t)4 * PL * 4;  // 2 hi planes + 2 lo planes
  const size_t fixed = ((size_t)NG * ND + 2 * (size_t)NG * NH) * 2 /*wih*/ +
                       3 * (size_t)NG * NH * 2 /*whh*/ +
                       (size_t)NB * NT * NH * 2 /*h*/ + 3 * exq_layer;
  int Tc = 128;
  while (Tc > 16 && fixed + (size_t)NB * Tc * NG * 2 > ws_size) Tc >>= 1;
  const int nc = NT / Tc;
  int tsh = 0;
  while ((1 << tsh) < Tc) tsh++;

  char* p = (char*)d_ws;
  size_t off = 0;
  f16* wih_f[3]; f16* whh_f[3];
  const int wih_sz[3] = {NG * ND, NG * NH, NG * NH};
  for (int l = 0; l < 3; l++) {
    wih_f[l] = (f16*)(p + off); off += (size_t)wih_sz[l] * 2;
    whh_f[l] = (f16*)(p + off); off += (size_t)NG * NH * 2;
  }
  f16* h = (f16*)(p + off); off += (size_t)NB * NT * NH * 2;
  u32* exq0 = (u32*)(p + off);
  u32* exqH[3]; u32* exqL[3];
  for (int l = 0; l < 3; l++) {
    exqH[l] = (u32*)(p + off); off += (size_t)2 * PL * 4;
    exqL[l] = (u32*)(p + off); off += (size_t)2 * PL * 4;
  }
  f16* gx = (f16*)(p + off); off += (size_t)NB * Tc * NG * 2;

  // zero all tags each launch (kills cross-replay tag aliasing; deterministic)
  hipMemsetAsync(exq0, 0, 3 * exq_layer, stream);

  auto conv = [&](const float* src, f16* dst, int n) {
    int blocks = (n + 1023) / 1024; if (blocks > 2048) blocks = 2048;
    k_f32_to_f16<<<dim3(blocks), dim3(256), 0, stream>>>(src, dst, n);
  };
  for (int l = 0; l < 3; l++) {
    conv(w_ih[l], wih_f[l], wih_sz[l]);
    conv(w_hh[l], whh_f[l], NG * NH);
  }

  const int mblocks = (NB * Tc) / 128;
  for (int c = 0; c < nc; c++) {
    const int t0 = c * Tc;
    k_gemm<ND, float><<<dim3(mblocks, 24), dim3(256), 0, stream>>>(x, wih_f[0], b_ih[0], gx, t0, tsh);
    k_rec<<<dim3(128), dim3(256), 0, stream>>>(gx, whh_f[0], b_hh[0], h, exqH[0], exqL[0], t0, Tc);
    k_gemm<NH, f16><<<dim3(mblocks, 24), dim3(256), 0, stream>>>(h, wih_f[1], b_ih[1], gx, t0, tsh);
    k_rec<<<dim3(128), dim3(256), 0, stream>>>(gx, whh_f[1], b_hh[1], h, exqH[1], exqL[1], t0, Tc);
    k_gemm<NH, f16><<<dim3(mblocks, 24), dim3(256), 0, stream>>>(h, wih_f[2], b_ih[2], gx, t0, tsh);
    k_rec<<<dim3(128), dim3(256), 0, stream>>>(gx, whh_f[2], b_hh[2], h, exqH[2], exqL[2], t0, Tc);
  }
  k_fc<<<dim3(NB), dim3(64), 0, stream>>>(h, fcw, fcb, (float*)d_out);
}

// Round 11
// 5045.094 us; speedup vs baseline: 1.9920x; 1.9920x over previous
//
#include <hip/hip_runtime.h>
#include <cstdint>
#include <cstddef>

typedef _Float16 f16;
typedef _Float16 f16x8 __attribute__((ext_vector_type(8)));
typedef float f32x4 __attribute__((ext_vector_type(4)));
typedef unsigned int u32;
typedef unsigned short u16;
typedef u32 u32x4 __attribute__((ext_vector_type(4)));

#define NB 256
#define NT 256
#define ND 128
#define NH 512
#define NG 1536
#define NOUT 24
#define PL (NB * NH)  // one packed exchange plane (u32 elements)

__device__ __forceinline__ float fsig(float x) {
  float e = __expf(-x);
  return __fdividef(1.0f, 1.0f + e);
}
__device__ __forceinline__ float ftanh(float x) {
  float ax = __builtin_fabsf(x);
  float e = __expf(-2.0f * ax);
  float t = __fdividef(1.0f - e, 1.0f + e);
  return __builtin_copysignf(t, x);
}
__device__ __forceinline__ u16 f16bits(f16 v) {
  union { f16 f; u16 s; } u; u.f = v; return u.s;
}

__global__ void k_f32_to_f16(const float* __restrict__ in, f16* __restrict__ out, int n) {
  int stride = gridDim.x * blockDim.x;
  for (int i = blockIdx.x * blockDim.x + threadIdx.x; i < n; i += stride)
    out[i] = (f16)in[i];
}

__device__ __forceinline__ f16x8 ld8(const f16* p) { return *(const f16x8*)p; }
__device__ __forceinline__ f16x8 ld8(const float* p) {
  float4 a = *(const float4*)p;
  float4 b = *(const float4*)(p + 4);
  f16x8 o;
  o[0] = (f16)a.x; o[1] = (f16)a.y; o[2] = (f16)a.z; o[3] = (f16)a.w;
  o[4] = (f16)b.x; o[5] = (f16)b.y; o[6] = (f16)b.z; o[7] = (f16)b.w;
  return o;
}

// ---- gx = A @ W^T + b. M-index r -> batch b=r>>tsh, local t = r&mask. (proven r7-r9)
template <int K, typename TA>
__global__ __launch_bounds__(256) void k_gemm(
    const TA* __restrict__ A, const f16* __restrict__ W,
    const float* __restrict__ bias, f16* __restrict__ gx, int t0, int tsh) {
  const int tid = threadIdx.x;
  const int wave = tid >> 6, lane = tid & 63;
  const int wm = wave >> 1, wn = wave & 1;
  const int m0 = blockIdx.x * 128 + wm * 64;
  const int n0 = blockIdx.y * 64 + wn * 32;
  const int lr = lane & 15;
  const int lk = (lane >> 4) * 8;
  const int tmask = (1 << tsh) - 1;

  f32x4 acc[4][2];
#pragma unroll
  for (int i = 0; i < 4; i++)
#pragma unroll
    for (int jj = 0; jj < 2; jj++) acc[i][jj] = (f32x4){0.f, 0.f, 0.f, 0.f};

  const TA* Ap[4];
#pragma unroll
  for (int i = 0; i < 4; i++) {
    int r = m0 + i * 16 + lr;
    int arow = ((r >> tsh) << 8) + t0 + (r & tmask);
    Ap[i] = A + (size_t)arow * K + lk;
  }
  const f16* Wp = W + (size_t)(n0 + lr) * K + lk;
  for (int k0 = 0; k0 < K; k0 += 32) {
    f16x8 a[4], b[2];
#pragma unroll
    for (int i = 0; i < 4; i++) a[i] = ld8(Ap[i] + k0);
#pragma unroll
    for (int jj = 0; jj < 2; jj++) b[jj] = *(const f16x8*)(Wp + (size_t)(jj * 16) * K + k0);
#pragma unroll
    for (int i = 0; i < 4; i++)
#pragma unroll
      for (int jj = 0; jj < 2; jj++)
        acc[i][jj] = __builtin_amdgcn_mfma_f32_16x16x32_f16(a[i], b[jj], acc[i][jj], 0, 0, 0);
  }
  const int rowb = (lane >> 4) * 4;
#pragma unroll
  for (int jj = 0; jj < 2; jj++) {
    int col = n0 + jj * 16 + lr;
    float bv = bias[col];
#pragma unroll
    for (int i = 0; i < 4; i++)
#pragma unroll
      for (int r = 0; r < 4; r++) {
        int row = m0 + i * 16 + rowb + r;
        gx[(size_t)row * NG + col] = (f16)(acc[i][jj][r] + bv);
      }
  }
}

// issue one 4-kk batch (8 dwordx4, system-coherent) from packed plane
#define ISSUE4K(qarr, kkb)                                               \
  _Pragma("unroll") for (int u_ = 0; u_ < 4; u_++) {                     \
    const u32* pp_ = hq + (kkb + u_) * 32 + lkh * 8;                     \
    asm volatile("global_load_dwordx4 %0, %1, off sc0 sc1"               \
                 : "=v"(qarr[2 * u_]) : "v"(pp_));                       \
    asm volatile("global_load_dwordx4 %0, %1, off sc0 sc1"               \
                 : "=v"(qarr[2 * u_ + 1]) : "v"(pp_ + 4));               \
  }

// consume one 4-kk batch: unpack hi/lo, 12 MFMA per kk (3 gates x 2 coltiles x hi/lo)
#define CONS4K(qarr, kkb)                                                            \
  _Pragma("unroll") for (int u_ = 0; u_ < 4; u_++) {                                 \
    const int kk_ = kkb + u_;                                                        \
    union { u32 w[4]; f16x8 v; } AH_, AL_;                                           \
    AH_.w[0] = __builtin_amdgcn_perm(qarr[2*u_][1],   qarr[2*u_][0],   0x05040100u); \
    AH_.w[1] = __builtin_amdgcn_perm(qarr[2*u_][3],   qarr[2*u_][2],   0x05040100u); \
    AH_.w[2] = __builtin_amdgcn_perm(qarr[2*u_+1][1], qarr[2*u_+1][0], 0x05040100u); \
    AH_.w[3] = __builtin_amdgcn_perm(qarr[2*u_+1][3], qarr[2*u_+1][2], 0x05040100u); \
    AL_.w[0] = __builtin_amdgcn_perm(qarr[2*u_][1],   qarr[2*u_][0],   0x07060302u); \
    AL_.w[1] = __builtin_amdgcn_perm(qarr[2*u_][3],   qarr[2*u_][2],   0x07060302u); \
    AL_.w[2] = __builtin_amdgcn_perm(qarr[2*u_+1][1], qarr[2*u_+1][0], 0x07060302u); \
    AL_.w[3] = __builtin_amdgcn_perm(qarr[2*u_+1][3], qarr[2*u_+1][2], 0x07060302u); \
    const int co_ = (((kk_ * 4 + lkh) ^ swz) << 3);                                  \
    f16x8 bro_ = *(const f16x8*)(wro_ + co_);                                        \
    f16x8 bzo_ = *(const f16x8*)(wzo_ + co_);                                        \
    f16x8 bno_ = *(const f16x8*)(wno_ + co_);                                        \
    f16x8 brx_ = *(const f16x8*)(wrx_ + co_);                                        \
    f16x8 bzx_ = *(const f16x8*)(wzx_ + co_);                                        \
    f16x8 bnx_ = *(const f16x8*)(wnx_ + co_);                                        \
    aRo = __builtin_amdgcn_mfma_f32_16x16x32_f16(AH_.v, bro_, aRo, 0, 0, 0);         \
    aZo = __builtin_amdgcn_mfma_f32_16x16x32_f16(AH_.v, bzo_, aZo, 0, 0, 0);         \
    aNo = __builtin_amdgcn_mfma_f32_16x16x32_f16(AH_.v, bno_, aNo, 0, 0, 0);         \
    aRx = __builtin_amdgcn_mfma_f32_16x16x32_f16(AH_.v, brx_, aRx, 0, 0, 0);         \
    aZx = __builtin_amdgcn_mfma_f32_16x16x32_f16(AH_.v, bzx_, aZx, 0, 0, 0);         \
    aNx = __builtin_amdgcn_mfma_f32_16x16x32_f16(AH_.v, bnx_, aNx, 0, 0, 0);         \
    aRo = __builtin_amdgcn_mfma_f32_16x16x32_f16(AL_.v, bro_, aRo, 0, 0, 0);         \
    aZo = __builtin_amdgcn_mfma_f32_16x16x32_f16(AL_.v, bzo_, aZo, 0, 0, 0);         \
    aNo = __builtin_amdgcn_mfma_f32_16x16x32_f16(AL_.v, bno_, aNo, 0, 0, 0);         \
    aRx = __builtin_amdgcn_mfma_f32_16x16x32_f16(AL_.v, brx_, aRx, 0, 0, 0);         \
    aZx = __builtin_amdgcn_mfma_f32_16x16x32_f16(AL_.v, bzx_, aZx, 0, 0, 0);         \
    aNx = __builtin_amdgcn_mfma_f32_16x16x32_f16(AL_.v, bnx_, aNx, 0, 0, 0);         \
  }

// ---- GRU recurrence over one time chunk. 128 blocks = 8 groups x 16 slices, 256 thr.
// Wave (wm,ks): rows wm-half, K-half ks, partials for BOTH 16-col tiles; cross-wave
// K-combine via LDS. Packed (hi|lo) u32 exchange plane at agent scope, batched
// pipelined dwordx4 loads. Single-cacheline flag barrier per group.
__global__ __launch_bounds__(256, 1) void k_rec(
    const f16* __restrict__ gx, const f16* __restrict__ whh, const float* __restrict__ bhh,
    f16* __restrict__ h, u32* __restrict__ exq, u32* __restrict__ fl,
    int t0, int Tc, int bar_base) {
  __shared__ f16 wlds[96 * 512];
  __shared__ float plds[2][2][64][12];
  const int tid = threadIdx.x;
  const int g = blockIdx.x >> 4;
  const int cs = blockIdx.x & 15;
  const int b0 = g * 32, c0 = cs * 32;
  const int lane = tid & 63, wave = tid >> 6;
  const int wm = wave >> 1, ks = wave & 1;
  const int lr = lane & 15, lkh = lane >> 4;
  const int first = (t0 == 0) ? 1 : 0;

  for (int idx = tid; idx < 96 * 64; idx += 256) {
    int lrw = idx >> 6, c = idx & 63;
    int grow = (lrw >> 5) * NH + c0 + (lrw & 31);
    f16x8 v = *(const f16x8*)(whh + (size_t)grow * NH + c * 8);
    *(f16x8*)(wlds + lrw * 512 + ((c ^ (lrw & 7)) << 3)) = v;
  }
  __syncthreads();

  const int jo = ks * 16 + lr;        // own coltile local col
  const int jx = (1 - ks) * 16 + lr;  // other coltile local col
  const int j = c0 + jo;
  const float bh_r = bhh[j], bh_z = bhh[NH + j], bh_n = bhh[2 * NH + j];
  const int arow = b0 + wm * 16 + lr;
  const int rowbase = b0 + wm * 16 + lkh * 4;
  const int swz = lr & 7;             // (16+lr)&7 == lr&7 -> same for both tiles
  const f16* wro_ = wlds + jo * 512;
  const f16* wzo_ = wlds + (32 + jo) * 512;
  const f16* wno_ = wlds + (64 + jo) * 512;
  const f16* wrx_ = wlds + jx * 512;
  const f16* wzx_ = wlds + (32 + jx) * 512;
  const f16* wnx_ = wlds + (64 + jx) * 512;
  const int ks8 = ks * 8;
  u32* myflag = fl + g * 64 + cs;     // 16 flags share one 64B line per group
  u32* gflags = fl + g * 64;
  const int pl = lane & 15;

  union PK2 { u32 u; f16 hh[2]; };

  float hold[4];
  if (first) {
#pragma unroll
    for (int r = 0; r < 4; r++) hold[r] = 0.f;
  } else {
#pragma unroll
    for (int r = 0; r < 4; r++) {
      PK2 pk;
      pk.u = __hip_atomic_load(exq + (size_t)(rowbase + r) * NH + j,
                               __ATOMIC_RELAXED, __HIP_MEMORY_SCOPE_AGENT);
      hold[r] = (float)pk.hh[0] + (float)pk.hh[1];
    }
  }

  // gx prefetch for t=0
  float xr[4], xz[4], xn[4];
#pragma unroll
  for (int r = 0; r < 4; r++) {
    const f16* gp = gx + ((size_t)(rowbase + r) * Tc) * NG + j;
    xr[r] = (float)gp[0]; xz[r] = (float)gp[NH]; xn[r] = (float)gp[2 * NH];
  }

  int cur = 0;
  for (int t = 0; t < Tc; t++) {
    f32x4 aRo = {0.f, 0.f, 0.f, 0.f}, aZo = {0.f, 0.f, 0.f, 0.f}, aNo = {0.f, 0.f, 0.f, 0.f};
    f32x4 aRx = {0.f, 0.f, 0.f, 0.f}, aZx = {0.f, 0.f, 0.f, 0.f}, aNx = {0.f, 0.f, 0.f, 0.f};
    if (t > 0 || !first) {
      const u32* hq = exq + (size_t)cur * PL + (size_t)arow * NH;
      u32x4 q0[8], q1[8];
      ISSUE4K(q0, ks8);
      ISSUE4K(q1, ks8 + 4);
      asm volatile("s_waitcnt vmcnt(8)" ::: "memory");
      __builtin_amdgcn_sched_barrier(0);
      CONS4K(q0, ks8);
      asm volatile("s_waitcnt vmcnt(0)" ::: "memory");
      __builtin_amdgcn_sched_barrier(0);
      CONS4K(q1, ks8 + 4);
      // cross-wave K-combine: export other-coltile partials, import partner's
      float* ps = &plds[wm][ks][lane][0];
#pragma unroll
      for (int i = 0; i < 4; i++) {
        ps[i] = aRx[i]; ps[4 + i] = aZx[i]; ps[8 + i] = aNx[i];
      }
      __syncthreads();
      const float* pr = &plds[wm][1 - ks][lane][0];
#pragma unroll
      for (int i = 0; i < 4; i++) {
        aRo[i] += pr[i]; aZo[i] += pr[4 + i]; aNo[i] += pr[8 + i];
      }
    }
    u32* outq = exq + (size_t)(cur ^ 1) * PL;
    f16 hhi_s[4];
#pragma unroll
    for (int r = 0; r < 4; r++) {
      float rg = fsig(xr[r] + aRo[r] + bh_r);
      float zg = fsig(xz[r] + aZo[r] + bh_z);
      float ng = ftanh(xn[r] + rg * (aNo[r] + bh_n));
      float hnew = ng + zg * (hold[r] - ng);
      hold[r] = hnew;
      PK2 pk;
      pk.hh[0] = (f16)hnew;
      pk.hh[1] = (f16)(hnew - (float)pk.hh[0]);
      hhi_s[r] = pk.hh[0];
      __hip_atomic_store(outq + (size_t)(rowbase + r) * NH + j, pk.u,
                         __ATOMIC_RELAXED, __HIP_MEMORY_SCOPE_AGENT);
    }
    if (t < Tc - 1) {
      asm volatile("s_waitcnt vmcnt(0)" ::: "memory");  // exchange stores at MALL
      __syncthreads();
      if (tid == 0)
        __hip_atomic_store(myflag, (u32)(bar_base + t + 1),
                           __ATOMIC_RELAXED, __HIP_MEMORY_SCOPE_AGENT);
      // hout + next gx prefetch hidden under the poll
#pragma unroll
      for (int r = 0; r < 4; r++)
        h[((size_t)(rowbase + r) * NT + (t0 + t)) * NH + j] = hhi_s[r];
#pragma unroll
      for (int r = 0; r < 4; r++) {
        const f16* gp = gx + ((size_t)(rowbase + r) * Tc + (t + 1)) * NG + j;
        xr[r] = (float)gp[0]; xz[r] = (float)gp[NH]; xn[r] = (float)gp[2 * NH];
      }
      asm volatile("" ::: "memory");
      const u32 target = (u32)(bar_base + t + 1);
      for (;;) {
        u32 v = __hip_atomic_load(gflags + pl,
                                  __ATOMIC_RELAXED, __HIP_MEMORY_SCOPE_AGENT);
        if (__all(v >= target)) break;
        __builtin_amdgcn_s_sleep(1);
      }
      asm volatile("" ::: "memory");
    } else {
#pragma unroll
      for (int r = 0; r < 4; r++)
        h[((size_t)(rowbase + r) * NT + (t0 + t)) * NH + j] = hhi_s[r];
    }
    cur ^= 1;
  }
}

// ---- final FC
__global__ void k_fc(const f16* __restrict__ h, const float* __restrict__ fcw,
                     const float* __restrict__ fcb, float* __restrict__ out) {
  int b = blockIdx.x;
  int lane = threadIdx.x;  // 64
  __shared__ float hrow[NH];
  for (int k = lane; k < NH; k += 64)
    hrow[k] = (float)h[((size_t)b * NT + (NT - 1)) * NH + k];
  __syncthreads();
  for (int o = 0; o < NOUT; o++) {
    float sm = 0.f;
    for (int k = lane; k < NH; k += 64) sm += hrow[k] * fcw[o * NH + k];
#pragma unroll
    for (int off = 32; off; off >>= 1) sm += __shfl_down(sm, off);
    if (lane == 0) out[b * NOUT + o] = sm + fcb[o];
  }
}

extern "C" void kernel_launch(void* const* d_in, const int* in_sizes, int n_in,
                              void* d_out, int out_size, void* d_ws, size_t ws_size,
                              hipStream_t stream) {
  (void)in_sizes; (void)n_in; (void)out_size;
  const float* x = (const float*)d_in[0];
  const float* w_ih[3] = {(const float*)d_in[1], (const float*)d_in[5], (const float*)d_in[9]};
  const float* w_hh[3] = {(const float*)d_in[2], (const float*)d_in[6], (const float*)d_in[10]};
  const float* b_ih[3] = {(const float*)d_in[3], (const float*)d_in[7], (const float*)d_in[11]};
  const float* b_hh[3] = {(const float*)d_in[4], (const float*)d_in[8], (const float*)d_in[12]};
  const float* fcw = (const float*)d_in[13];
  const float* fcb = (const float*)d_in[14];

  const size_t fixed = 32768 +
                       ((size_t)NG * ND + 2 * (size_t)NG * NH) * 2 /*wih*/ +
                       3 * (size_t)NG * NH * 2 /*whh*/ +
                       (size_t)NB * NT * NH * 2 /*h*/ +
                       3 * (size_t)2 * PL * 4 /*exq*/;
  int Tc = 128;
  while (Tc > 16 && fixed + (size_t)NB * Tc * NG * 2 > ws_size) Tc >>= 1;
  const int nc = NT / Tc;
  int tsh = 0;
  while ((1 << tsh) < Tc) tsh++;

  char* p = (char*)d_ws;
  size_t off = 0;
  u32* ctrl = (u32*)(p + off); off += 32768;  // 3 layers x 8 groups x 64B flag line
  f16* wih_f[3]; f16* whh_f[3];
  const int wih_sz[3] = {NG * ND, NG * NH, NG * NH};
  for (int l = 0; l < 3; l++) {
    wih_f[l] = (f16*)(p + off); off += (size_t)wih_sz[l] * 2;
    whh_f[l] = (f16*)(p + off); off += (size_t)NG * NH * 2;
  }
  f16* h = (f16*)(p + off); off += (size_t)NB * NT * NH * 2;
  u32* exq[3];
  for (int l = 0; l < 3; l++) {
    exq[l] = (u32*)(p + off); off += (size_t)2 * PL * 4;
  }
  f16* gx = (f16*)(p + off); off += (size_t)NB * Tc * NG * 2;

  hipMemsetAsync(ctrl, 0, 32768, stream);

  auto conv = [&](const float* src, f16* dst, int n) {
    int blocks = (n + 1023) / 1024; if (blocks > 2048) blocks = 2048;
    k_f32_to_f16<<<dim3(blocks), dim3(256), 0, stream>>>(src, dst, n);
  };
  for (int l = 0; l < 3; l++) {
    conv(w_ih[l], wih_f[l], wih_sz[l]);
    conv(w_hh[l], whh_f[l], NG * NH);
  }

  const int mblocks = (NB * Tc) / 128;
  for (int c = 0; c < nc; c++) {
    const int t0 = c * Tc;
    const int bar_base = c * (Tc - 1);
    k_gemm<ND, float><<<dim3(mblocks, 24), dim3(256), 0, stream>>>(x, wih_f[0], b_ih[0], gx, t0, tsh);
    k_rec<<<dim3(128), dim3(256), 0, stream>>>(
        gx, whh_f[0], b_hh[0], h, exq[0], ctrl + 0 * 512, t0, Tc, bar_base);
    k_gemm<NH, f16><<<dim3(mblocks, 24), dim3(256), 0, stream>>>(h, wih_f[1], b_ih[1], gx, t0, tsh);
    k_rec<<<dim3(128), dim3(256), 0, stream>>>(
        gx, whh_f[1], b_hh[1], h, exq[1], ctrl + 1 * 512, t0, Tc, bar_base);
    k_gemm<NH, f16><<<dim3(mblocks, 24), dim3(256), 0, stream>>>(h, wih_f[2], b_ih[2], gx, t0, tsh);
    k_rec<<<dim3(128), dim3(256), 0, stream>>>(
        gx, whh_f[2], b_hh[2], h, exq[2], ctrl + 2 * 512, t0, Tc, bar_base);
  }
  k_fc<<<dim3(NB), dim3(64), 0, stream>>>(h, fcw, fcb, (float*)d_out);
}

// Round 12
// 3592.705 us; speedup vs baseline: 2.7973x; 1.4043x over previous
//
#include <hip/hip_runtime.h>
#include <cstdint>
#include <cstddef>

typedef _Float16 f16;
typedef _Float16 f16x8 __attribute__((ext_vector_type(8)));
typedef float f32x4 __attribute__((ext_vector_type(4)));
typedef unsigned int u32;
typedef unsigned short u16;
typedef u32 u32x4 __attribute__((ext_vector_type(4)));

#define NB 256
#define NT 256
#define ND 128
#define NH 512
#define NG 1536
#define NOUT 24
#define PL (NB * NH)  // one packed exchange plane (u32 elements)

__device__ __forceinline__ float fsig(float x) {
  float e = __expf(-x);
  return __fdividef(1.0f, 1.0f + e);
}
__device__ __forceinline__ float ftanh(float x) {
  float ax = __builtin_fabsf(x);
  float e = __expf(-2.0f * ax);
  float t = __fdividef(1.0f - e, 1.0f + e);
  return __builtin_copysignf(t, x);
}

__global__ void k_f32_to_f16(const float* __restrict__ in, f16* __restrict__ out, int n) {
  int stride = gridDim.x * blockDim.x;
  for (int i = blockIdx.x * blockDim.x + threadIdx.x; i < n; i += stride)
    out[i] = (f16)in[i];
}

__device__ __forceinline__ f16x8 ld8(const f16* p) { return *(const f16x8*)p; }
__device__ __forceinline__ f16x8 ld8(const float* p) {
  float4 a = *(const float4*)p;
  float4 b = *(const float4*)(p + 4);
  f16x8 o;
  o[0] = (f16)a.x; o[1] = (f16)a.y; o[2] = (f16)a.z; o[3] = (f16)a.w;
  o[4] = (f16)b.x; o[5] = (f16)b.y; o[6] = (f16)b.z; o[7] = (f16)b.w;
  return o;
}

// ---- gx = A @ W^T + b. M-index r -> batch b=r>>tsh, local t = r&mask. (proven r7-r11)
template <int K, typename TA>
__global__ __launch_bounds__(256) void k_gemm(
    const TA* __restrict__ A, const f16* __restrict__ W,
    const float* __restrict__ bias, f16* __restrict__ gx, int t0, int tsh) {
  const int tid = threadIdx.x;
  const int wave = tid >> 6, lane = tid & 63;
  const int wm = wave >> 1, wn = wave & 1;
  const int m0 = blockIdx.x * 128 + wm * 64;
  const int n0 = blockIdx.y * 64 + wn * 32;
  const int lr = lane & 15;
  const int lk = (lane >> 4) * 8;
  const int tmask = (1 << tsh) - 1;

  f32x4 acc[4][2];
#pragma unroll
  for (int i = 0; i < 4; i++)
#pragma unroll
    for (int jj = 0; jj < 2; jj++) acc[i][jj] = (f32x4){0.f, 0.f, 0.f, 0.f};

  const TA* Ap[4];
#pragma unroll
  for (int i = 0; i < 4; i++) {
    int r = m0 + i * 16 + lr;
    int arow = ((r >> tsh) << 8) + t0 + (r & tmask);
    Ap[i] = A + (size_t)arow * K + lk;
  }
  const f16* Wp = W + (size_t)(n0 + lr) * K + lk;
  for (int k0 = 0; k0 < K; k0 += 32) {
    f16x8 a[4], b[2];
#pragma unroll
    for (int i = 0; i < 4; i++) a[i] = ld8(Ap[i] + k0);
#pragma unroll
    for (int jj = 0; jj < 2; jj++) b[jj] = *(const f16x8*)(Wp + (size_t)(jj * 16) * K + k0);
#pragma unroll
    for (int i = 0; i < 4; i++)
#pragma unroll
      for (int jj = 0; jj < 2; jj++)
        acc[i][jj] = __builtin_amdgcn_mfma_f32_16x16x32_f16(a[i], b[jj], acc[i][jj], 0, 0, 0);
  }
  const int rowb = (lane >> 4) * 4;
#pragma unroll
  for (int jj = 0; jj < 2; jj++) {
    int col = n0 + jj * 16 + lr;
    float bv = bias[col];
#pragma unroll
    for (int i = 0; i < 4; i++)
#pragma unroll
      for (int r = 0; r < 4; r++) {
        int row = m0 + i * 16 + rowb + r;
        gx[(size_t)row * NG + col] = (f16)(acc[i][jj][r] + bv);
      }
  }
}

// issue one 4-kk batch (8 dwordx4, system-coherent) from packed plane
#define ISSUE4K(qarr, kkb)                                               \
  _Pragma("unroll") for (int u_ = 0; u_ < 4; u_++) {                     \
    const u32* pp_ = hq + (kkb + u_) * 32 + lkh * 8;                     \
    asm volatile("global_load_dwordx4 %0, %1, off sc0 sc1"               \
                 : "=v"(qarr[2 * u_]) : "v"(pp_));                       \
    asm volatile("global_load_dwordx4 %0, %1, off sc0 sc1"               \
                 : "=v"(qarr[2 * u_ + 1]) : "v"(pp_ + 4));               \
  }

// consume one 4-kk batch: unpack hi/lo, 12 MFMA per kk (3 gates x 2 coltiles x hi/lo)
#define CONS4K(qarr, kkb)                                                            \
  _Pragma("unroll") for (int u_ = 0; u_ < 4; u_++) {                                 \
    const int kk_ = kkb + u_;                                                        \
    union { u32 w[4]; f16x8 v; } AH_, AL_;                                           \
    AH_.w[0] = __builtin_amdgcn_perm(qarr[2*u_][1],   qarr[2*u_][0],   0x05040100u); \
    AH_.w[1] = __builtin_amdgcn_perm(qarr[2*u_][3],   qarr[2*u_][2],   0x05040100u); \
    AH_.w[2] = __builtin_amdgcn_perm(qarr[2*u_+1][1], qarr[2*u_+1][0], 0x05040100u); \
    AH_.w[3] = __builtin_amdgcn_perm(qarr[2*u_+1][3], qarr[2*u_+1][2], 0x05040100u); \
    AL_.w[0] = __builtin_amdgcn_perm(qarr[2*u_][1],   qarr[2*u_][0],   0x07060302u); \
    AL_.w[1] = __builtin_amdgcn_perm(qarr[2*u_][3],   qarr[2*u_][2],   0x07060302u); \
    AL_.w[2] = __builtin_amdgcn_perm(qarr[2*u_+1][1], qarr[2*u_+1][0], 0x07060302u); \
    AL_.w[3] = __builtin_amdgcn_perm(qarr[2*u_+1][3], qarr[2*u_+1][2], 0x07060302u); \
    const int co_ = (((kk_ * 4 + lkh) ^ swz) << 3);                                  \
    f16x8 bro_ = *(const f16x8*)(wro_ + co_);                                        \
    f16x8 bzo_ = *(const f16x8*)(wzo_ + co_);                                        \
    f16x8 bno_ = *(const f16x8*)(wno_ + co_);                                        \
    f16x8 brx_ = *(const f16x8*)(wrx_ + co_);                                        \
    f16x8 bzx_ = *(const f16x8*)(wzx_ + co_);                                        \
    f16x8 bnx_ = *(const f16x8*)(wnx_ + co_);                                        \
    aRo = __builtin_amdgcn_mfma_f32_16x16x32_f16(AH_.v, bro_, aRo, 0, 0, 0);         \
    aZo = __builtin_amdgcn_mfma_f32_16x16x32_f16(AH_.v, bzo_, aZo, 0, 0, 0);         \
    aNo = __builtin_amdgcn_mfma_f32_16x16x32_f16(AH_.v, bno_, aNo, 0, 0, 0);         \
    aRx = __builtin_amdgcn_mfma_f32_16x16x32_f16(AH_.v, brx_, aRx, 0, 0, 0);         \
    aZx = __builtin_amdgcn_mfma_f32_16x16x32_f16(AH_.v, bzx_, aZx, 0, 0, 0);         \
    aNx = __builtin_amdgcn_mfma_f32_16x16x32_f16(AH_.v, bnx_, aNx, 0, 0, 0);         \
    aRo = __builtin_amdgcn_mfma_f32_16x16x32_f16(AL_.v, bro_, aRo, 0, 0, 0);         \
    aZo = __builtin_amdgcn_mfma_f32_16x16x32_f16(AL_.v, bzo_, aZo, 0, 0, 0);         \
    aNo = __builtin_amdgcn_mfma_f32_16x16x32_f16(AL_.v, bno_, aNo, 0, 0, 0);         \
    aRx = __builtin_amdgcn_mfma_f32_16x16x32_f16(AL_.v, brx_, aRx, 0, 0, 0);         \
    aZx = __builtin_amdgcn_mfma_f32_16x16x32_f16(AL_.v, bzx_, aZx, 0, 0, 0);         \
    aNx = __builtin_amdgcn_mfma_f32_16x16x32_f16(AL_.v, bnx_, aNx, 0, 0, 0);         \
  }

struct RecUnit {
  const f16* gx; const f16* whh; const float* bhh;
  u32* exq; u32* fl; int t0; int bar_base;
};

// ---- GRU recurrence, r11 core + unit dimension (<=2 independent 128-block units
// per launch for layer-chunk pipelining). Per unit: 8 groups x 16 slices; K-split
// waves; LDS K-combine; packed hi|lo agent-scope exchange; 1-line flag barrier.
__global__ __launch_bounds__(256, 1) void k_rec(
    RecUnit u0, RecUnit u1, f16* __restrict__ h, int Tc) {
  __shared__ f16 wlds[96 * 512];
  __shared__ float plds[2][2][64][12];
  const RecUnit U = (blockIdx.x < 128) ? u0 : u1;
  const int bid = blockIdx.x & 127;
  const f16* __restrict__ gx = U.gx;
  u32* __restrict__ exq = U.exq;
  const int t0 = U.t0, bar_base = U.bar_base;
  const int tid = threadIdx.x;
  const int g = bid >> 4;
  const int cs = bid & 15;
  const int b0 = g * 32, c0 = cs * 32;
  const int lane = tid & 63, wave = tid >> 6;
  const int wm = wave >> 1, ks = wave & 1;
  const int lr = lane & 15, lkh = lane >> 4;
  const int first = (t0 == 0) ? 1 : 0;

  for (int idx = tid; idx < 96 * 64; idx += 256) {
    int lrw = idx >> 6, c = idx & 63;
    int grow = (lrw >> 5) * NH + c0 + (lrw & 31);
    f16x8 v = *(const f16x8*)(U.whh + (size_t)grow * NH + c * 8);
    *(f16x8*)(wlds + lrw * 512 + ((c ^ (lrw & 7)) << 3)) = v;
  }
  __syncthreads();

  const int jo = ks * 16 + lr;
  const int jx = (1 - ks) * 16 + lr;
  const int j = c0 + jo;
  const float bh_r = U.bhh[j], bh_z = U.bhh[NH + j], bh_n = U.bhh[2 * NH + j];
  const int arow = b0 + wm * 16 + lr;
  const int rowbase = b0 + wm * 16 + lkh * 4;
  const int swz = lr & 7;
  const f16* wro_ = wlds + jo * 512;
  const f16* wzo_ = wlds + (32 + jo) * 512;
  const f16* wno_ = wlds + (64 + jo) * 512;
  const f16* wrx_ = wlds + jx * 512;
  const f16* wzx_ = wlds + (32 + jx) * 512;
  const f16* wnx_ = wlds + (64 + jx) * 512;
  const int ks8 = ks * 8;
  u32* myflag = U.fl + g * 64 + cs;
  u32* gflags = U.fl + g * 64;
  const int pl = lane & 15;

  union PK2 { u32 u; f16 hh[2]; };

  float hold[4];
  if (first) {
#pragma unroll
    for (int r = 0; r < 4; r++) hold[r] = 0.f;
  } else {
#pragma unroll
    for (int r = 0; r < 4; r++) {
      PK2 pk;
      pk.u = __hip_atomic_load(exq + (size_t)(rowbase + r) * NH + j,
                               __ATOMIC_RELAXED, __HIP_MEMORY_SCOPE_AGENT);
      hold[r] = (float)pk.hh[0] + (float)pk.hh[1];
    }
  }

  float xr[4], xz[4], xn[4];
#pragma unroll
  for (int r = 0; r < 4; r++) {
    const f16* gp = gx + ((size_t)(rowbase + r) * Tc) * NG + j;
    xr[r] = (float)gp[0]; xz[r] = (float)gp[NH]; xn[r] = (float)gp[2 * NH];
  }

  int cur = 0;
  for (int t = 0; t < Tc; t++) {
    f32x4 aRo = {0.f, 0.f, 0.f, 0.f}, aZo = {0.f, 0.f, 0.f, 0.f}, aNo = {0.f, 0.f, 0.f, 0.f};
    f32x4 aRx = {0.f, 0.f, 0.f, 0.f}, aZx = {0.f, 0.f, 0.f, 0.f}, aNx = {0.f, 0.f, 0.f, 0.f};
    if (t > 0 || !first) {
      const u32* hq = exq + (size_t)cur * PL + (size_t)arow * NH;
      u32x4 q0[8], q1[8];
      ISSUE4K(q0, ks8);
      ISSUE4K(q1, ks8 + 4);
      asm volatile("s_waitcnt vmcnt(8)" ::: "memory");
      __builtin_amdgcn_sched_barrier(0);
      CONS4K(q0, ks8);
      asm volatile("s_waitcnt vmcnt(0)" ::: "memory");
      __builtin_amdgcn_sched_barrier(0);
      CONS4K(q1, ks8 + 4);
      float* ps = &plds[wm][ks][lane][0];
#pragma unroll
      for (int i = 0; i < 4; i++) {
        ps[i] = aRx[i]; ps[4 + i] = aZx[i]; ps[8 + i] = aNx[i];
      }
      __syncthreads();
      const float* pr = &plds[wm][1 - ks][lane][0];
#pragma unroll
      for (int i = 0; i < 4; i++) {
        aRo[i] += pr[i]; aZo[i] += pr[4 + i]; aNo[i] += pr[8 + i];
      }
    }
    u32* outq = exq + (size_t)(cur ^ 1) * PL;
    f16 hhi_s[4];
#pragma unroll
    for (int r = 0; r < 4; r++) {
      float rg = fsig(xr[r] + aRo[r] + bh_r);
      float zg = fsig(xz[r] + aZo[r] + bh_z);
      float ng = ftanh(xn[r] + rg * (aNo[r] + bh_n));
      float hnew = ng + zg * (hold[r] - ng);
      hold[r] = hnew;
      PK2 pk;
      pk.hh[0] = (f16)hnew;
      pk.hh[1] = (f16)(hnew - (float)pk.hh[0]);
      hhi_s[r] = pk.hh[0];
      __hip_atomic_store(outq + (size_t)(rowbase + r) * NH + j, pk.u,
                         __ATOMIC_RELAXED, __HIP_MEMORY_SCOPE_AGENT);
    }
    if (t < Tc - 1) {
      asm volatile("s_waitcnt vmcnt(0)" ::: "memory");
      __syncthreads();
      if (tid == 0)
        __hip_atomic_store(myflag, (u32)(bar_base + t + 1),
                           __ATOMIC_RELAXED, __HIP_MEMORY_SCOPE_AGENT);
#pragma unroll
      for (int r = 0; r < 4; r++)
        h[((size_t)(rowbase + r) * NT + (t0 + t)) * NH + j] = hhi_s[r];
#pragma unroll
      for (int r = 0; r < 4; r++) {
        const f16* gp = gx + ((size_t)(rowbase + r) * Tc + (t + 1)) * NG + j;
        xr[r] = (float)gp[0]; xz[r] = (float)gp[NH]; xn[r] = (float)gp[2 * NH];
      }
      asm volatile("" ::: "memory");
      const u32 target = (u32)(bar_base + t + 1);
      for (;;) {
        u32 v = __hip_atomic_load(gflags + pl,
                                  __ATOMIC_RELAXED, __HIP_MEMORY_SCOPE_AGENT);
        if (__all(v >= target)) break;
        __builtin_amdgcn_s_sleep(1);
      }
      asm volatile("" ::: "memory");
    } else {
#pragma unroll
      for (int r = 0; r < 4; r++)
        h[((size_t)(rowbase + r) * NT + (t0 + t)) * NH + j] = hhi_s[r];
    }
    cur ^= 1;
  }
}

// ---- final FC
__global__ void k_fc(const f16* __restrict__ h, const float* __restrict__ fcw,
                     const float* __restrict__ fcb, float* __restrict__ out) {
  int b = blockIdx.x;
  int lane = threadIdx.x;  // 64
  __shared__ float hrow[NH];
  for (int k = lane; k < NH; k += 64)
    hrow[k] = (float)h[((size_t)b * NT + (NT - 1)) * NH + k];
  __syncthreads();
  for (int o = 0; o < NOUT; o++) {
    float sm = 0.f;
    for (int k = lane; k < NH; k += 64) sm += hrow[k] * fcw[o * NH + k];
#pragma unroll
    for (int off = 32; off; off >>= 1) sm += __shfl_down(sm, off);
    if (lane == 0) out[b * NOUT + o] = sm + fcb[o];
  }
}

extern "C" void kernel_launch(void* const* d_in, const int* in_sizes, int n_in,
                              void* d_out, int out_size, void* d_ws, size_t ws_size,
                              hipStream_t stream) {
  (void)in_sizes; (void)n_in; (void)out_size;
  const float* x = (const float*)d_in[0];
  const float* w_ih[3] = {(const float*)d_in[1], (const float*)d_in[5], (const float*)d_in[9]};
  const float* w_hh[3] = {(const float*)d_in[2], (const float*)d_in[6], (const float*)d_in[10]};
  const float* b_ih[3] = {(const float*)d_in[3], (const float*)d_in[7], (const float*)d_in[11]};
  const float* b_hh[3] = {(const float*)d_in[4], (const float*)d_in[8], (const float*)d_in[12]};
  const float* fcw = (const float*)d_in[13];
  const float* fcb = (const float*)d_in[14];

  const size_t fixed = 32768 +
                       ((size_t)NG * ND + 2 * (size_t)NG * NH) * 2 /*wih*/ +
                       3 * (size_t)NG * NH * 2 /*whh*/ +
                       (size_t)NB * NT * NH * 2 /*h*/ +
                       3 * (size_t)2 * PL * 4 /*exq*/;
  int Tc = 64;  // pipeline-friendly chunk; 2 gx buffers
  while (Tc > 16 && fixed + 2 * ((size_t)NB * Tc * NG * 2) > ws_size) Tc >>= 1;
  const int nc = NT / Tc;
  int tsh = 0;
  while ((1 << tsh) < Tc) tsh++;

  char* p = (char*)d_ws;
  size_t off = 0;
  u32* ctrl = (u32*)(p + off); off += 32768;  // 3 layers x 8 groups x 64B flag line
  f16* wih_f[3]; f16* whh_f[3];
  const int wih_sz[3] = {NG * ND, NG * NH, NG * NH};
  for (int l = 0; l < 3; l++) {
    wih_f[l] = (f16*)(p + off); off += (size_t)wih_sz[l] * 2;
    whh_f[l] = (f16*)(p + off); off += (size_t)NG * NH * 2;
  }
  f16* h = (f16*)(p + off); off += (size_t)NB * NT * NH * 2;
  u32* exq[3];
  for (int l = 0; l < 3; l++) {
    exq[l] = (u32*)(p + off); off += (size_t)2 * PL * 4;
  }
  f16* gxbuf[2];
  for (int s = 0; s < 2; s++) {
    gxbuf[s] = (f16*)(p + off); off += (size_t)NB * Tc * NG * 2;
  }

  hipMemsetAsync(ctrl, 0, 32768, stream);

  auto conv = [&](const float* src, f16* dst, int n) {
    int blocks = (n + 1023) / 1024; if (blocks > 2048) blocks = 2048;
    k_f32_to_f16<<<dim3(blocks), dim3(256), 0, stream>>>(src, dst, n);
  };
  for (int l = 0; l < 3; l++) {
    conv(w_ih[l], wih_f[l], wih_sz[l]);
    conv(w_hh[l], whh_f[l], NG * NH);
  }

  const int mblocks = (NB * Tc) / 128;

  // ---- greedy pair schedule over the 3 x nc wavefront ----
  bool done[3][16] = {};
  int completed = 0, total = 3 * nc;
  while (completed < total) {
    int pl_[2], pc_[2], np = 0;
    bool picked[3][16] = {};
    for (int s = 0; s < 2; s++) {
      int bl = -1, bc = -1, bk = 1 << 30;
      for (int l = 0; l < 3; l++)
        for (int c = 0; c < nc; c++) {
          if (done[l][c] || picked[l][c]) continue;
          if (l > 0 && !done[l - 1][c]) continue;
          if (c > 0 && !done[l][c - 1]) continue;
          int key = (l + c) * 4 + l;
          if (key < bk) { bk = key; bl = l; bc = c; }
        }
      if (bl < 0) break;
      picked[bl][bc] = true;
      pl_[np] = bl; pc_[np] = bc; np++;
    }
    // gemms for this wave's units (stream-ordered before the merged rec)
    for (int s = 0; s < np; s++) {
      int l = pl_[s], c = pc_[s];
      if (l == 0)
        k_gemm<ND, float><<<dim3(mblocks, 24), dim3(256), 0, stream>>>(
            x, wih_f[0], b_ih[0], gxbuf[s], c * Tc, tsh);
      else
        k_gemm<NH, f16><<<dim3(mblocks, 24), dim3(256), 0, stream>>>(
            h, wih_f[l], b_ih[l], gxbuf[s], c * Tc, tsh);
    }
    RecUnit us[2];
    for (int s = 0; s < np; s++) {
      int l = pl_[s], c = pc_[s];
      us[s].gx = gxbuf[s];
      us[s].whh = whh_f[l];
      us[s].bhh = b_hh[l];
      us[s].exq = exq[l];
      us[s].fl = ctrl + l * 512;
      us[s].t0 = c * Tc;
      us[s].bar_base = c * (Tc - 1);
    }
    if (np == 1) us[1] = us[0];
    k_rec<<<dim3(np * 128), dim3(256), 0, stream>>>(us[0], us[1], h, Tc);
    for (int s = 0; s < np; s++) { done[pl_[s]][pc_[s]] = true; completed++; }
  }
  k_fc<<<dim3(NB), dim3(64), 0, stream>>>(h, fcw, fcb, (float*)d_out);
}